// Round 1
// baseline (810.187 us; speedup 1.0000x reference)
//
#include <hip/hip_runtime.h>
#include <hip/hip_bf16.h>

#define N_TOK 4096
#define DIMD  1024
#define HDIM  4096
#define NEXP  8
#define MAXSLOT 9216   // 8192 pairs + up to 8*127 padding, rounded to 128
#define MAXTILE 72     // MAXSLOT / 128

typedef __attribute__((ext_vector_type(4))) float f32x4;
typedef __attribute__((ext_vector_type(8))) short bf16x8;

__device__ __forceinline__ ushort f2bf(float f) {
    __hip_bfloat16 h = __float2bfloat16(f);
    return *reinterpret_cast<ushort*>(&h);
}

// ---------------- router: logits, softmax, top2, aux partials, x->bf16 ----------------
__global__ __launch_bounds__(256) void router_kernel(
    const float* __restrict__ x, const float* __restrict__ rw,
    ushort* __restrict__ xbf, int* __restrict__ tok_e, float* __restrict__ tok_w,
    float* __restrict__ aux_f, int* __restrict__ aux_i)
{
    int wave = threadIdx.x >> 6, lane = threadIdx.x & 63;
    int token = blockIdx.x * 4 + wave;
    float acc[NEXP];
#pragma unroll
    for (int e = 0; e < NEXP; ++e) acc[e] = 0.f;
    const float* xr = x + (size_t)token * DIMD;
    for (int it = 0; it < DIMD / 64; ++it) {
        int d = it * 64 + lane;
        float xv = xr[d];
        xbf[(size_t)token * DIMD + d] = f2bf(xv);
#pragma unroll
        for (int e = 0; e < NEXP; ++e) acc[e] += xv * rw[e * DIMD + d];
    }
#pragma unroll
    for (int e = 0; e < NEXP; ++e) {
        float v = acc[e];
        for (int off = 32; off; off >>= 1) v += __shfl_xor(v, off);
        acc[e] = v;
    }
    float m = acc[0];
#pragma unroll
    for (int e = 1; e < NEXP; ++e) m = fmaxf(m, acc[e]);
    float p[NEXP], s = 0.f;
#pragma unroll
    for (int e = 0; e < NEXP; ++e) { p[e] = expf(acc[e] - m); s += p[e]; }
    float lse = m + logf(s);
    float inv = 1.f / s;
    int i1 = 0; float b1 = p[0];
#pragma unroll
    for (int e = 1; e < NEXP; ++e) if (p[e] > b1) { b1 = p[e]; i1 = e; }
    int i2 = -1; float b2 = -1.f;
#pragma unroll
    for (int e = 0; e < NEXP; ++e) if (e != i1 && p[e] > b2) { b2 = p[e]; i2 = e; }
    float wsum = b1 + b2;
    float w1 = b1 / wsum, w2 = b2 / wsum;
    if (lane == 0) {
        tok_e[token * 2] = i1; tok_e[token * 2 + 1] = i2;
        tok_w[token * 2] = w1; tok_w[token * 2 + 1] = w2;
    }
    __shared__ float s_imp[NEXP]; __shared__ float s_z;
    __shared__ int s_c1[NEXP], s_c2[NEXP];
    if (threadIdx.x < NEXP) { s_imp[threadIdx.x] = 0.f; s_c1[threadIdx.x] = 0; s_c2[threadIdx.x] = 0; }
    if (threadIdx.x == 0) s_z = 0.f;
    __syncthreads();
    if (lane == 0) {
#pragma unroll
        for (int e = 0; e < NEXP; ++e) atomicAdd(&s_imp[e], p[e] * inv);
        atomicAdd(&s_z, lse * lse);
        atomicAdd(&s_c1[i1], 1);
        atomicAdd(&s_c2[i1], 1);
        atomicAdd(&s_c2[i2], 1);
    }
    __syncthreads();
    if (threadIdx.x < NEXP) {
        atomicAdd(&aux_f[threadIdx.x], s_imp[threadIdx.x]);
        atomicAdd(&aux_i[threadIdx.x], s_c1[threadIdx.x]);
        atomicAdd(&aux_i[NEXP + threadIdx.x], s_c2[threadIdx.x]);
    }
    if (threadIdx.x == 0) atomicAdd(&aux_f[NEXP], s_z);
}

// ---------------- finalize: losses to d_out tail, slot offsets, tile->expert ----------------
__global__ void finalize_kernel(const float* __restrict__ aux_f, const int* __restrict__ aux_i,
                                float* __restrict__ out_tail, int* __restrict__ offsets,
                                int* __restrict__ cursor, int* __restrict__ tile_e)
{
    if (threadIdx.x != 0 || blockIdx.x != 0) return;
    float imp[NEXP];
    float lb = 0.f, isum = 0.f;
    for (int e = 0; e < NEXP; ++e) {
        imp[e] = aux_f[e];
        isum += imp[e];
        lb += (float)aux_i[e] * imp[e];
    }
    lb *= (float)NEXP / ((float)N_TOK * (float)N_TOK);
    float zl = aux_f[NEXP] / (float)N_TOK;
    float mean = isum / (float)NEXP;
    float var = 0.f;
    for (int e = 0; e < NEXP; ++e) { float d = imp[e] - mean; var += d * d; }
    var /= (float)(NEXP - 1);
    out_tail[0] = lb;
    out_tail[1] = zl;
    out_tail[2] = var;
    for (int e = 0; e < NEXP; ++e) out_tail[3 + e] = (float)aux_i[e];

    int off = 0;
    for (int e = 0; e < NEXP; ++e) {
        offsets[e] = off;
        off += ((aux_i[NEXP + e] + 127) >> 7) << 7;
    }
    offsets[NEXP] = off;
    int ntile = off >> 7;
    for (int tt = 0; tt < MAXTILE; ++tt) {
        int e = -1;
        if (tt < ntile) {
            for (int j = 0; j < NEXP; ++j)
                if (tt * 128 >= offsets[j] && tt * 128 < offsets[j + 1]) e = j;
        }
        tile_e[tt] = e;
    }
    for (int e = 0; e < NEXP; ++e) cursor[e] = 0;
}

// ---------------- fill: compact (token,k) pairs into per-expert slot ranges ----------------
__global__ void fill_kernel(const int* __restrict__ tok_e, const float* __restrict__ tok_w,
                            const int* __restrict__ offsets, int* __restrict__ cursor,
                            int* __restrict__ slot_token, float* __restrict__ slot_wt)
{
    int t = blockIdx.x * 256 + threadIdx.x;
    if (t >= N_TOK) return;
    for (int k = 0; k < 2; ++k) {
        int e = tok_e[t * 2 + k];
        int pos = atomicAdd(&cursor[e], 1);
        int slot = offsets[e] + pos;
        slot_token[slot] = t;
        slot_wt[slot] = tok_w[t * 2 + k];
    }
}

// ---------------- weight pre-conversion ----------------
// wup[e][h][d] = bf16(wsu[d][h] + wru[e][d][h])   (transposed so GEMM stages with b128 copies)
__global__ __launch_bounds__(256) void convert_up(const float* __restrict__ wsu,
                                                  const float* __restrict__ wru,
                                                  ushort* __restrict__ wup)
{
    int e = blockIdx.z;
    int h0 = blockIdx.x * 64, d0 = blockIdx.y * 64;
    __shared__ float tile[64][65];
    int c = threadIdx.x & 63, r4 = threadIdx.x >> 6;
#pragma unroll
    for (int it = 0; it < 16; ++it) {
        int r = it * 4 + r4;
        size_t gi = ((size_t)(d0 + r)) * HDIM + h0 + c;
        tile[r][c] = wsu[gi] + wru[(size_t)e * DIMD * HDIM + gi];
    }
    __syncthreads();
#pragma unroll
    for (int it = 0; it < 16; ++it) {
        int hr = it * 4 + r4;
        float v = tile[c][hr];
        wup[((size_t)e * HDIM + h0 + hr) * DIMD + d0 + c] = f2bf(v);
    }
}

// wdn[e][d][h] = bf16(wsd[d][h] + wrd[e][d][h])   (no transpose needed)
__global__ void convert_dn(const float* __restrict__ wsd, const float* __restrict__ wrd,
                           ushort* __restrict__ wdn)
{
    size_t i = ((size_t)blockIdx.x * 256 + threadIdx.x) * 4;
    float4 a = *(const float4*)(wrd + i);
    float4 b = *(const float4*)(wsd + (i & (size_t)0x3FFFFF)); // i mod 2^22 (D*H)
    ushort4 o;
    o.x = f2bf(a.x + b.x); o.y = f2bf(a.y + b.y);
    o.z = f2bf(a.z + b.z); o.w = f2bf(a.w + b.w);
    *(ushort4*)(wdn + i) = o;
}

// ---------------- up GEMM: h = relu(x @ Wup_e)^2, bf16 out ----------------
__global__ __launch_bounds__(256) void up_gemm(
    const ushort* __restrict__ xbf, const ushort* __restrict__ wup,
    const int* __restrict__ slot_token, const int* __restrict__ tile_e,
    ushort* __restrict__ hbf)
{
    int bt = blockIdx.y;
    int e = tile_e[bt];
    if (e < 0) return;
    int h0 = blockIdx.x * 128;
    __shared__ ushort As[128 * 72];
    __shared__ ushort Bs[128 * 72];
    __shared__ int stok[128];
    int t = threadIdx.x;
    if (t < 128) stok[t] = slot_token[bt * 128 + t];
    int wave = t >> 6, lane = t & 63;
    int wm = (wave >> 1) << 6, wn = (wave & 1) << 6;
    int l15 = lane & 15, q = lane >> 4;
    f32x4 acc[4][4] = {};
    const ushort* wb = wup + ((size_t)e * HDIM + h0) * DIMD;
    for (int k0 = 0; k0 < DIMD; k0 += 64) {
        __syncthreads();
#pragma unroll
        for (int it = 0; it < 4; ++it) {
            int seg = t + it * 256;
            int r = seg >> 3, part = seg & 7;
            int tok = stok[r];
            int4 v = {0, 0, 0, 0};
            if (tok >= 0) v = *(const int4*)(xbf + (size_t)tok * DIMD + k0 + part * 8);
            *(int4*)(As + r * 72 + part * 8) = v;
            int4 w = *(const int4*)(wb + (size_t)r * DIMD + k0 + part * 8);
            *(int4*)(Bs + r * 72 + part * 8) = w;
        }
        __syncthreads();
#pragma unroll
        for (int kk = 0; kk < 64; kk += 32) {
            int ko = kk + q * 8;
            bf16x8 a[4], b[4];
#pragma unroll
            for (int i = 0; i < 4; ++i) a[i] = *(const bf16x8*)(As + (wm + i * 16 + l15) * 72 + ko);
#pragma unroll
            for (int j = 0; j < 4; ++j) b[j] = *(const bf16x8*)(Bs + (wn + j * 16 + l15) * 72 + ko);
#pragma unroll
            for (int i = 0; i < 4; ++i)
#pragma unroll
                for (int j = 0; j < 4; ++j)
                    acc[i][j] = __builtin_amdgcn_mfma_f32_16x16x32_bf16(a[i], b[j], acc[i][j], 0, 0, 0);
        }
    }
    size_t rowbase = (size_t)bt * 128;
#pragma unroll
    for (int i = 0; i < 4; ++i) {
        int row = wm + i * 16 + q * 4;
#pragma unroll
        for (int r = 0; r < 4; ++r) {
            size_t rb = (rowbase + row + r) * HDIM + h0;
#pragma unroll
            for (int j = 0; j < 4; ++j) {
                float v = acc[i][j][r];
                v = fmaxf(v, 0.f); v = v * v;
                hbf[rb + wn + j * 16 + l15] = f2bf(v);
            }
        }
    }
}

// ---------------- down GEMM: out[token] += wt * (h @ Wdn_e^T) ----------------
__global__ __launch_bounds__(256) void down_gemm(
    const ushort* __restrict__ hbf, const ushort* __restrict__ wdn,
    const int* __restrict__ slot_token, const float* __restrict__ slot_wt,
    const int* __restrict__ tile_e, float* __restrict__ out)
{
    int bt = blockIdx.y;
    int e = tile_e[bt];
    if (e < 0) return;
    int d0 = blockIdx.x * 128;
    __shared__ ushort As[128 * 72];
    __shared__ ushort Bs[128 * 72];
    __shared__ int stok[128];
    __shared__ float swt[128];
    int t = threadIdx.x;
    if (t < 128) { stok[t] = slot_token[bt * 128 + t]; swt[t] = slot_wt[bt * 128 + t]; }
    int wave = t >> 6, lane = t & 63;
    int wm = (wave >> 1) << 6, wn = (wave & 1) << 6;
    int l15 = lane & 15, q = lane >> 4;
    f32x4 acc[4][4] = {};
    const ushort* ab = hbf + (size_t)bt * 128 * HDIM;
    const ushort* wb = wdn + ((size_t)e * DIMD + d0) * HDIM;
    for (int k0 = 0; k0 < HDIM; k0 += 64) {
        __syncthreads();
#pragma unroll
        for (int it = 0; it < 4; ++it) {
            int seg = t + it * 256;
            int r = seg >> 3, part = seg & 7;
            *(int4*)(As + r * 72 + part * 8) = *(const int4*)(ab + (size_t)r * HDIM + k0 + part * 8);
            *(int4*)(Bs + r * 72 + part * 8) = *(const int4*)(wb + (size_t)r * HDIM + k0 + part * 8);
        }
        __syncthreads();
#pragma unroll
        for (int kk = 0; kk < 64; kk += 32) {
            int ko = kk + q * 8;
            bf16x8 a[4], b[4];
#pragma unroll
            for (int i = 0; i < 4; ++i) a[i] = *(const bf16x8*)(As + (wm + i * 16 + l15) * 72 + ko);
#pragma unroll
            for (int j = 0; j < 4; ++j) b[j] = *(const bf16x8*)(Bs + (wn + j * 16 + l15) * 72 + ko);
#pragma unroll
            for (int i = 0; i < 4; ++i)
#pragma unroll
                for (int j = 0; j < 4; ++j)
                    acc[i][j] = __builtin_amdgcn_mfma_f32_16x16x32_bf16(a[i], b[j], acc[i][j], 0, 0, 0);
        }
    }
#pragma unroll
    for (int i = 0; i < 4; ++i) {
#pragma unroll
        for (int r = 0; r < 4; ++r) {
            int row = wm + i * 16 + q * 4 + r;
            int tok = stok[row];
            if (tok < 0) continue;
            float wgt = swt[row];
            float* orow = out + (size_t)tok * DIMD + d0 + wn;
#pragma unroll
            for (int j = 0; j < 4; ++j)
                atomicAdd(orow + j * 16 + l15, wgt * acc[i][j][r]);
        }
    }
}

extern "C" void kernel_launch(void* const* d_in, const int* in_sizes, int n_in,
                              void* d_out, int out_size, void* d_ws, size_t ws_size,
                              hipStream_t stream)
{
    const float* x   = (const float*)d_in[0];
    const float* rw  = (const float*)d_in[1];
    const float* wsu = (const float*)d_in[2];
    const float* wsd = (const float*)d_in[3];
    const float* wru = (const float*)d_in[4];
    const float* wrd = (const float*)d_in[5];
    float* out = (float*)d_out;

    char* ws = (char*)d_ws;
    size_t off = 0;
    auto alloc = [&](size_t b) { size_t o = off; off = (off + b + 255) & ~(size_t)255; return o; };
    float* aux_f     = (float*)(ws + alloc(16 * 4));          // imp[8], z
    int*   aux_i     = (int*)(ws + alloc(16 * 4));            // cnt1[8], cnt2[8]
    int*   tok_e     = (int*)(ws + alloc(N_TOK * 2 * 4));
    float* tok_w     = (float*)(ws + alloc(N_TOK * 2 * 4));
    int*   offsets   = (int*)(ws + alloc(16 * 4));
    int*   cursor    = (int*)(ws + alloc(8 * 4));
    int*   tile_e    = (int*)(ws + alloc(128 * 4));
    int*   slot_token= (int*)(ws + alloc(MAXSLOT * 4));
    float* slot_wt   = (float*)(ws + alloc(MAXSLOT * 4));
    ushort* xbf      = (ushort*)(ws + alloc((size_t)N_TOK * DIMD * 2));
    ushort* wup      = (ushort*)(ws + alloc((size_t)NEXP * HDIM * DIMD * 2));
    ushort* wdn      = (ushort*)(ws + alloc((size_t)NEXP * DIMD * HDIM * 2));
    ushort* hbf      = (ushort*)(ws + alloc((size_t)MAXSLOT * HDIM * 2));
    (void)ws_size; (void)in_sizes; (void)n_in;

    hipMemsetAsync(d_out, 0, (size_t)out_size * 4, stream);
    hipMemsetAsync(aux_f, 0, 16 * 4, stream);
    hipMemsetAsync(aux_i, 0, 16 * 4, stream);
    hipMemsetAsync(slot_token, 0xFF, MAXSLOT * 4, stream);

    router_kernel<<<N_TOK / 4, 256, 0, stream>>>(x, rw, xbf, tok_e, tok_w, aux_f, aux_i);
    finalize_kernel<<<1, 64, 0, stream>>>(aux_f, aux_i, out + (size_t)N_TOK * DIMD,
                                          offsets, cursor, tile_e);
    fill_kernel<<<N_TOK / 256, 256, 0, stream>>>(tok_e, tok_w, offsets, cursor, slot_token, slot_wt);
    convert_up<<<dim3(HDIM / 64, DIMD / 64, NEXP), 256, 0, stream>>>(wsu, wru, wup);
    convert_dn<<<(NEXP * DIMD * HDIM) / (256 * 4), 256, 0, stream>>>(wsd, wrd, wdn);
    up_gemm<<<dim3(HDIM / 128, MAXTILE), 256, 0, stream>>>(xbf, wup, slot_token, tile_e, hbf);
    down_gemm<<<dim3(DIMD / 128, MAXTILE), 256, 0, stream>>>(hbf, wdn, slot_token, slot_wt, tile_e, out);
}

// Round 2
// 697.536 us; speedup vs baseline: 1.1615x; 1.1615x over previous
//
#include <hip/hip_runtime.h>
#include <hip/hip_bf16.h>

#define N_TOK 4096
#define DIMD  1024
#define HDIM  4096
#define NEXP  8
#define MAXSLOT 9216   // 8192 pairs + up to 8*127 padding, rounded to 128
#define MAXTILE 72     // MAXSLOT / 128

typedef __attribute__((ext_vector_type(4))) float f32x4;
typedef __attribute__((ext_vector_type(8))) short bf16x8;

__device__ __forceinline__ ushort f2bf(float f) {
    __hip_bfloat16 h = __float2bfloat16(f);
    return *reinterpret_cast<ushort*>(&h);
}

// async global->LDS, 16B per lane; LDS dst = wave-uniform base + lane*16
__device__ __forceinline__ void async_copy16(const ushort* g, ushort* l) {
    __builtin_amdgcn_global_load_lds((const __attribute__((address_space(1))) void*)g,
                                     (__attribute__((address_space(3))) void*)l,
                                     16, 0, 0);
}

// ---------------- router: logits, softmax, top2, aux partials, x->bf16 ----------------
__global__ __launch_bounds__(256) void router_kernel(
    const float* __restrict__ x, const float* __restrict__ rw,
    ushort* __restrict__ xbf, int* __restrict__ tok_e, float* __restrict__ tok_w,
    float* __restrict__ aux_f, int* __restrict__ aux_i)
{
    int wave = threadIdx.x >> 6, lane = threadIdx.x & 63;
    int token = blockIdx.x * 4 + wave;
    float acc[NEXP];
#pragma unroll
    for (int e = 0; e < NEXP; ++e) acc[e] = 0.f;
    const float* xr = x + (size_t)token * DIMD;
    for (int it = 0; it < DIMD / 64; ++it) {
        int d = it * 64 + lane;
        float xv = xr[d];
        xbf[(size_t)token * DIMD + d] = f2bf(xv);
#pragma unroll
        for (int e = 0; e < NEXP; ++e) acc[e] += xv * rw[e * DIMD + d];
    }
#pragma unroll
    for (int e = 0; e < NEXP; ++e) {
        float v = acc[e];
        for (int off = 32; off; off >>= 1) v += __shfl_xor(v, off);
        acc[e] = v;
    }
    float m = acc[0];
#pragma unroll
    for (int e = 1; e < NEXP; ++e) m = fmaxf(m, acc[e]);
    float p[NEXP], s = 0.f;
#pragma unroll
    for (int e = 0; e < NEXP; ++e) { p[e] = expf(acc[e] - m); s += p[e]; }
    float lse = m + logf(s);
    float inv = 1.f / s;
    int i1 = 0; float b1 = p[0];
#pragma unroll
    for (int e = 1; e < NEXP; ++e) if (p[e] > b1) { b1 = p[e]; i1 = e; }
    int i2 = -1; float b2 = -1.f;
#pragma unroll
    for (int e = 0; e < NEXP; ++e) if (e != i1 && p[e] > b2) { b2 = p[e]; i2 = e; }
    float wsum = b1 + b2;
    float w1 = b1 / wsum, w2 = b2 / wsum;
    if (lane == 0) {
        tok_e[token * 2] = i1; tok_e[token * 2 + 1] = i2;
        tok_w[token * 2] = w1; tok_w[token * 2 + 1] = w2;
    }
    __shared__ float s_imp[NEXP]; __shared__ float s_z;
    __shared__ int s_c1[NEXP], s_c2[NEXP];
    if (threadIdx.x < NEXP) { s_imp[threadIdx.x] = 0.f; s_c1[threadIdx.x] = 0; s_c2[threadIdx.x] = 0; }
    if (threadIdx.x == 0) s_z = 0.f;
    __syncthreads();
    if (lane == 0) {
#pragma unroll
        for (int e = 0; e < NEXP; ++e) atomicAdd(&s_imp[e], p[e] * inv);
        atomicAdd(&s_z, lse * lse);
        atomicAdd(&s_c1[i1], 1);
        atomicAdd(&s_c2[i1], 1);
        atomicAdd(&s_c2[i2], 1);
    }
    __syncthreads();
    if (threadIdx.x < NEXP) {
        atomicAdd(&aux_f[threadIdx.x], s_imp[threadIdx.x]);
        atomicAdd(&aux_i[threadIdx.x], s_c1[threadIdx.x]);
        atomicAdd(&aux_i[NEXP + threadIdx.x], s_c2[threadIdx.x]);
    }
    if (threadIdx.x == 0) atomicAdd(&aux_f[NEXP], s_z);
}

// ---------------- finalize: losses to d_out tail, slot offsets, tile->expert ----------------
__global__ void finalize_kernel(const float* __restrict__ aux_f, const int* __restrict__ aux_i,
                                float* __restrict__ out_tail, int* __restrict__ offsets,
                                int* __restrict__ cursor, int* __restrict__ tile_e)
{
    if (threadIdx.x != 0 || blockIdx.x != 0) return;
    float imp[NEXP];
    float lb = 0.f, isum = 0.f;
    for (int e = 0; e < NEXP; ++e) {
        imp[e] = aux_f[e];
        isum += imp[e];
        lb += (float)aux_i[e] * imp[e];
    }
    lb *= (float)NEXP / ((float)N_TOK * (float)N_TOK);
    float zl = aux_f[NEXP] / (float)N_TOK;
    float mean = isum / (float)NEXP;
    float var = 0.f;
    for (int e = 0; e < NEXP; ++e) { float d = imp[e] - mean; var += d * d; }
    var /= (float)(NEXP - 1);
    out_tail[0] = lb;
    out_tail[1] = zl;
    out_tail[2] = var;
    for (int e = 0; e < NEXP; ++e) out_tail[3 + e] = (float)aux_i[e];

    int off = 0;
    for (int e = 0; e < NEXP; ++e) {
        offsets[e] = off;
        off += ((aux_i[NEXP + e] + 127) >> 7) << 7;
    }
    offsets[NEXP] = off;
    int ntile = off >> 7;
    for (int tt = 0; tt < MAXTILE; ++tt) {
        int e = -1;
        if (tt < ntile) {
            for (int j = 0; j < NEXP; ++j)
                if (tt * 128 >= offsets[j] && tt * 128 < offsets[j + 1]) e = j;
        }
        tile_e[tt] = e;
    }
    for (int e = 0; e < NEXP; ++e) cursor[e] = 0;
}

// ---------------- fill: compact (token,k) pairs into per-expert slot ranges ----------------
__global__ void fill_kernel(const int* __restrict__ tok_e, const float* __restrict__ tok_w,
                            const int* __restrict__ offsets, int* __restrict__ cursor,
                            int* __restrict__ slot_token, float* __restrict__ slot_wt)
{
    int t = blockIdx.x * 256 + threadIdx.x;
    if (t >= N_TOK) return;
    for (int k = 0; k < 2; ++k) {
        int e = tok_e[t * 2 + k];
        int pos = atomicAdd(&cursor[e], 1);
        int slot = offsets[e] + pos;
        slot_token[slot] = t;
        slot_wt[slot] = tok_w[t * 2 + k];
    }
}

// ---------------- weight pre-conversion ----------------
// wup[e][h][d] = bf16(wsu[d][h] + wru[e][d][h])   (transposed so GEMM B-tiles are row-contiguous)
__global__ __launch_bounds__(256) void convert_up(const float* __restrict__ wsu,
                                                  const float* __restrict__ wru,
                                                  ushort* __restrict__ wup)
{
    int e = blockIdx.z;
    int h0 = blockIdx.x * 64, d0 = blockIdx.y * 64;
    __shared__ float tile[64][65];      // tile[d_local][h_local]
    int c = threadIdx.x & 63, r4 = threadIdx.x >> 6;
#pragma unroll
    for (int it = 0; it < 16; ++it) {
        int r = it * 4 + r4;
        size_t gi = ((size_t)(d0 + r)) * HDIM + h0 + c;
        tile[r][c] = wsu[gi] + wru[(size_t)e * DIMD * HDIM + gi];
    }
    __syncthreads();
    int c4 = threadIdx.x & 15, rr = threadIdx.x >> 4;   // 16 d-groups x 16 h-rows
#pragma unroll
    for (int it = 0; it < 4; ++it) {
        int hr = it * 16 + rr;
        ushort4 o;
        o.x = f2bf(tile[c4 * 4 + 0][hr]);
        o.y = f2bf(tile[c4 * 4 + 1][hr]);
        o.z = f2bf(tile[c4 * 4 + 2][hr]);
        o.w = f2bf(tile[c4 * 4 + 3][hr]);
        *(ushort4*)(wup + ((size_t)e * HDIM + h0 + hr) * DIMD + d0 + c4 * 4) = o;
    }
}

// wdn[e][d][h] = bf16(wsd[d][h] + wrd[e][d][h])   (no transpose needed)
__global__ void convert_dn(const float* __restrict__ wsd, const float* __restrict__ wrd,
                           ushort* __restrict__ wdn)
{
    size_t i = ((size_t)blockIdx.x * 256 + threadIdx.x) * 4;
    float4 a = *(const float4*)(wrd + i);
    float4 b = *(const float4*)(wsd + (i & (size_t)0x3FFFFF)); // i mod 2^22 (D*H)
    ushort4 o;
    o.x = f2bf(a.x + b.x); o.y = f2bf(a.y + b.y);
    o.z = f2bf(a.z + b.z); o.w = f2bf(a.w + b.w);
    *(ushort4*)(wdn + i) = o;
}

// ---------------- up GEMM: h = relu(x @ Wup_e)^2, bf16 out ----------------
// LDS layout: row-major stride 64, with XOR swizzle folded into the *source*
// address of the DMA: LDS slot s of row r holds global part s^(r&7).
// Fragment reads then hit all 32 banks with 2 lanes/bank (free).
__global__ __launch_bounds__(256) void up_gemm(
    const ushort* __restrict__ xbf, const ushort* __restrict__ wup,
    const int* __restrict__ slot_token, const int* __restrict__ tile_e,
    ushort* __restrict__ hbf)
{
    int bt = blockIdx.y;
    int e = tile_e[bt];
    if (e < 0) return;
    int h0 = blockIdx.x * 128;
    __shared__ ushort As[128 * 64];
    __shared__ ushort Bs[128 * 64];
    int t = threadIdx.x;
    int wave = t >> 6, lane = t & 63;
    int s8 = lane & 7, r8 = lane >> 3;
    int p = s8 ^ r8;                       // swizzled source part for this lane
    const ushort* wb = wup + ((size_t)e * HDIM + h0) * DIMD;
    const ushort* aptr[4];
    const ushort* bptr[4];
#pragma unroll
    for (int cc = 0; cc < 4; ++cc) {
        int row = wave * 32 + cc * 8 + r8;
        int tok = slot_token[bt * 128 + row];
        if (tok < 0) tok = 0;              // padding rows: load anything valid, output discarded later
        aptr[cc] = xbf + (size_t)tok * DIMD + p * 8;
        bptr[cc] = wb + (size_t)row * DIMD + p * 8;
    }
    ushort* lA = As + wave * 4 * 512;      // 512 ushorts = 1 KB chunk (8 rows)
    ushort* lB = Bs + wave * 4 * 512;
    int wm = (wave >> 1) << 6, wn = (wave & 1) << 6;
    int l15 = lane & 15, q = lane >> 4;
    int r7 = l15 & 7;
    f32x4 acc[4][4] = {};
    for (int k0 = 0; k0 < DIMD; k0 += 64) {
        __syncthreads();
#pragma unroll
        for (int cc = 0; cc < 4; ++cc) {
            async_copy16(aptr[cc] + k0, lA + cc * 512);
            async_copy16(bptr[cc] + k0, lB + cc * 512);
        }
        __syncthreads();                   // drains vmcnt -> DMA visible
#pragma unroll
        for (int kk = 0; kk < 64; kk += 32) {
            int pr = (kk >> 3) + q;        // logical part 0..7
            int so = ((pr ^ r7) << 3);     // swizzled element offset in row
            bf16x8 a[4], b[4];
#pragma unroll
            for (int i = 0; i < 4; ++i) a[i] = *(const bf16x8*)(As + (wm + i * 16 + l15) * 64 + so);
#pragma unroll
            for (int j = 0; j < 4; ++j) b[j] = *(const bf16x8*)(Bs + (wn + j * 16 + l15) * 64 + so);
#pragma unroll
            for (int i = 0; i < 4; ++i)
#pragma unroll
                for (int j = 0; j < 4; ++j)
                    acc[i][j] = __builtin_amdgcn_mfma_f32_16x16x32_bf16(a[i], b[j], acc[i][j], 0, 0, 0);
        }
    }
    size_t rowbase = (size_t)bt * 128;
#pragma unroll
    for (int i = 0; i < 4; ++i) {
        int row = wm + i * 16 + q * 4;
#pragma unroll
        for (int r = 0; r < 4; ++r) {
            size_t rb = (rowbase + row + r) * HDIM + h0;
#pragma unroll
            for (int j = 0; j < 4; ++j) {
                float v = acc[i][j][r];
                v = fmaxf(v, 0.f); v = v * v;
                hbf[rb + wn + j * 16 + l15] = f2bf(v);
            }
        }
    }
}

// ---------------- down GEMM: out[token] += wt * (h @ Wdn_e^T), K-split x2 ----------------
__global__ __launch_bounds__(256) void down_gemm(
    const ushort* __restrict__ hbf, const ushort* __restrict__ wdn,
    const int* __restrict__ slot_token, const float* __restrict__ slot_wt,
    const int* __restrict__ tile_e, float* __restrict__ out)
{
    int bt = blockIdx.y;
    int e = tile_e[bt];
    if (e < 0) return;
    int d0 = blockIdx.x * 128;
    int kbase = blockIdx.z * (HDIM / 2);
    __shared__ ushort As[128 * 64];
    __shared__ ushort Bs[128 * 64];
    __shared__ int stok[128];
    __shared__ float swt[128];
    int t = threadIdx.x;
    if (t < 128) { stok[t] = slot_token[bt * 128 + t]; swt[t] = slot_wt[bt * 128 + t]; }
    int wave = t >> 6, lane = t & 63;
    int s8 = lane & 7, r8 = lane >> 3;
    int p = s8 ^ r8;
    const ushort* aptr[4];
    const ushort* bptr[4];
#pragma unroll
    for (int cc = 0; cc < 4; ++cc) {
        int row = wave * 32 + cc * 8 + r8;
        aptr[cc] = hbf + ((size_t)bt * 128 + row) * HDIM + p * 8;
        bptr[cc] = wdn + ((size_t)e * DIMD + d0 + row) * HDIM + p * 8;
    }
    ushort* lA = As + wave * 4 * 512;
    ushort* lB = Bs + wave * 4 * 512;
    int wm = (wave >> 1) << 6, wn = (wave & 1) << 6;
    int l15 = lane & 15, q = lane >> 4;
    int r7 = l15 & 7;
    f32x4 acc[4][4] = {};
    for (int k0 = kbase; k0 < kbase + HDIM / 2; k0 += 64) {
        __syncthreads();
#pragma unroll
        for (int cc = 0; cc < 4; ++cc) {
            async_copy16(aptr[cc] + k0, lA + cc * 512);
            async_copy16(bptr[cc] + k0, lB + cc * 512);
        }
        __syncthreads();
#pragma unroll
        for (int kk = 0; kk < 64; kk += 32) {
            int pr = (kk >> 3) + q;
            int so = ((pr ^ r7) << 3);
            bf16x8 a[4], b[4];
#pragma unroll
            for (int i = 0; i < 4; ++i) a[i] = *(const bf16x8*)(As + (wm + i * 16 + l15) * 64 + so);
#pragma unroll
            for (int j = 0; j < 4; ++j) b[j] = *(const bf16x8*)(Bs + (wn + j * 16 + l15) * 64 + so);
#pragma unroll
            for (int i = 0; i < 4; ++i)
#pragma unroll
                for (int j = 0; j < 4; ++j)
                    acc[i][j] = __builtin_amdgcn_mfma_f32_16x16x32_bf16(a[i], b[j], acc[i][j], 0, 0, 0);
        }
    }
#pragma unroll
    for (int i = 0; i < 4; ++i) {
#pragma unroll
        for (int r = 0; r < 4; ++r) {
            int row = wm + i * 16 + q * 4 + r;
            int tok = stok[row];
            if (tok < 0) continue;
            float wgt = swt[row];
            float* orow = out + (size_t)tok * DIMD + d0 + wn;
#pragma unroll
            for (int j = 0; j < 4; ++j)
                atomicAdd(orow + j * 16 + l15, wgt * acc[i][j][r]);
        }
    }
}

extern "C" void kernel_launch(void* const* d_in, const int* in_sizes, int n_in,
                              void* d_out, int out_size, void* d_ws, size_t ws_size,
                              hipStream_t stream)
{
    const float* x   = (const float*)d_in[0];
    const float* rw  = (const float*)d_in[1];
    const float* wsu = (const float*)d_in[2];
    const float* wsd = (const float*)d_in[3];
    const float* wru = (const float*)d_in[4];
    const float* wrd = (const float*)d_in[5];
    float* out = (float*)d_out;

    char* ws = (char*)d_ws;
    size_t off = 0;
    auto alloc = [&](size_t b) { size_t o = off; off = (off + b + 255) & ~(size_t)255; return o; };
    float* aux_f     = (float*)(ws + alloc(16 * 4));          // imp[8], z
    int*   aux_i     = (int*)(ws + alloc(16 * 4));            // cnt1[8], cnt2[8]
    int*   tok_e     = (int*)(ws + alloc(N_TOK * 2 * 4));
    float* tok_w     = (float*)(ws + alloc(N_TOK * 2 * 4));
    int*   offsets   = (int*)(ws + alloc(16 * 4));
    int*   cursor    = (int*)(ws + alloc(8 * 4));
    int*   tile_e    = (int*)(ws + alloc(128 * 4));
    int*   slot_token= (int*)(ws + alloc(MAXSLOT * 4));
    float* slot_wt   = (float*)(ws + alloc(MAXSLOT * 4));
    ushort* xbf      = (ushort*)(ws + alloc((size_t)N_TOK * DIMD * 2));
    ushort* wup      = (ushort*)(ws + alloc((size_t)NEXP * HDIM * DIMD * 2));
    ushort* wdn      = (ushort*)(ws + alloc((size_t)NEXP * DIMD * HDIM * 2));
    ushort* hbf      = (ushort*)(ws + alloc((size_t)MAXSLOT * HDIM * 2));
    (void)ws_size; (void)in_sizes; (void)n_in;

    hipMemsetAsync(d_out, 0, (size_t)out_size * 4, stream);
    hipMemsetAsync(aux_f, 0, 16 * 4, stream);
    hipMemsetAsync(aux_i, 0, 16 * 4, stream);
    hipMemsetAsync(slot_token, 0xFF, MAXSLOT * 4, stream);

    router_kernel<<<N_TOK / 4, 256, 0, stream>>>(x, rw, xbf, tok_e, tok_w, aux_f, aux_i);
    finalize_kernel<<<1, 64, 0, stream>>>(aux_f, aux_i, out + (size_t)N_TOK * DIMD,
                                          offsets, cursor, tile_e);
    fill_kernel<<<N_TOK / 256, 256, 0, stream>>>(tok_e, tok_w, offsets, cursor, slot_token, slot_wt);
    convert_up<<<dim3(HDIM / 64, DIMD / 64, NEXP), 256, 0, stream>>>(wsu, wru, wup);
    convert_dn<<<(NEXP * DIMD * HDIM) / (256 * 4), 256, 0, stream>>>(wsd, wrd, wdn);
    up_gemm<<<dim3(HDIM / 128, MAXTILE), 256, 0, stream>>>(xbf, wup, slot_token, tile_e, hbf);
    down_gemm<<<dim3(DIMD / 128, MAXTILE, 2), 256, 0, stream>>>(hbf, wdn, slot_token, slot_wt, tile_e, out);
}

// Round 3
// 673.696 us; speedup vs baseline: 1.2026x; 1.0354x over previous
//
#include <hip/hip_runtime.h>
#include <hip/hip_bf16.h>

#define N_TOK 4096
#define DIMD  1024
#define HDIM  4096
#define NEXP  8
#define MAXSLOT 10240  // 8192 pairs + up to 8*255 padding, rounded to 256
#define MAXTILE 40     // MAXSLOT / 256

typedef __attribute__((ext_vector_type(4))) float f32x4;
typedef __attribute__((ext_vector_type(8))) short bf16x8;

__device__ __forceinline__ ushort f2bf(float f) {
    __hip_bfloat16 h = __float2bfloat16(f);
    return *reinterpret_cast<ushort*>(&h);
}

// async global->LDS, 16B per lane; LDS dst = wave-uniform base + lane*16
__device__ __forceinline__ void async_copy16(const ushort* g, ushort* l) {
    __builtin_amdgcn_global_load_lds((const __attribute__((address_space(1))) void*)g,
                                     (__attribute__((address_space(3))) void*)l,
                                     16, 0, 0);
}

// ---------------- router: logits, softmax, top2, aux partials, x->bf16 ----------------
__global__ __launch_bounds__(256) void router_kernel(
    const float* __restrict__ x, const float* __restrict__ rw,
    ushort* __restrict__ xbf, int* __restrict__ tok_e, float* __restrict__ tok_w,
    float* __restrict__ aux_f, int* __restrict__ aux_i)
{
    int wave = threadIdx.x >> 6, lane = threadIdx.x & 63;
    int token = blockIdx.x * 4 + wave;
    float acc[NEXP];
#pragma unroll
    for (int e = 0; e < NEXP; ++e) acc[e] = 0.f;
    const float* xr = x + (size_t)token * DIMD;
    for (int it = 0; it < DIMD / 64; ++it) {
        int d = it * 64 + lane;
        float xv = xr[d];
        xbf[(size_t)token * DIMD + d] = f2bf(xv);
#pragma unroll
        for (int e = 0; e < NEXP; ++e) acc[e] += xv * rw[e * DIMD + d];
    }
#pragma unroll
    for (int e = 0; e < NEXP; ++e) {
        float v = acc[e];
        for (int off = 32; off; off >>= 1) v += __shfl_xor(v, off);
        acc[e] = v;
    }
    float m = acc[0];
#pragma unroll
    for (int e = 1; e < NEXP; ++e) m = fmaxf(m, acc[e]);
    float p[NEXP], s = 0.f;
#pragma unroll
    for (int e = 0; e < NEXP; ++e) { p[e] = expf(acc[e] - m); s += p[e]; }
    float lse = m + logf(s);
    float inv = 1.f / s;
    int i1 = 0; float b1 = p[0];
#pragma unroll
    for (int e = 1; e < NEXP; ++e) if (p[e] > b1) { b1 = p[e]; i1 = e; }
    int i2 = -1; float b2 = -1.f;
#pragma unroll
    for (int e = 0; e < NEXP; ++e) if (e != i1 && p[e] > b2) { b2 = p[e]; i2 = e; }
    float wsum = b1 + b2;
    float w1 = b1 / wsum, w2 = b2 / wsum;
    if (lane == 0) {
        tok_e[token * 2] = i1; tok_e[token * 2 + 1] = i2;
        tok_w[token * 2] = w1; tok_w[token * 2 + 1] = w2;
    }
    __shared__ float s_imp[NEXP]; __shared__ float s_z;
    __shared__ int s_c1[NEXP], s_c2[NEXP];
    if (threadIdx.x < NEXP) { s_imp[threadIdx.x] = 0.f; s_c1[threadIdx.x] = 0; s_c2[threadIdx.x] = 0; }
    if (threadIdx.x == 0) s_z = 0.f;
    __syncthreads();
    if (lane == 0) {
#pragma unroll
        for (int e = 0; e < NEXP; ++e) atomicAdd(&s_imp[e], p[e] * inv);
        atomicAdd(&s_z, lse * lse);
        atomicAdd(&s_c1[i1], 1);
        atomicAdd(&s_c2[i1], 1);
        atomicAdd(&s_c2[i2], 1);
    }
    __syncthreads();
    if (threadIdx.x < NEXP) {
        atomicAdd(&aux_f[threadIdx.x], s_imp[threadIdx.x]);
        atomicAdd(&aux_i[threadIdx.x], s_c1[threadIdx.x]);
        atomicAdd(&aux_i[NEXP + threadIdx.x], s_c2[threadIdx.x]);
    }
    if (threadIdx.x == 0) atomicAdd(&aux_f[NEXP], s_z);
}

// ---------------- finalize: losses to d_out tail, slot offsets (256-aligned), tile->expert --------
__global__ void finalize_kernel(const float* __restrict__ aux_f, const int* __restrict__ aux_i,
                                float* __restrict__ out_tail, int* __restrict__ offsets,
                                int* __restrict__ cursor, int* __restrict__ tile_e)
{
    if (threadIdx.x != 0 || blockIdx.x != 0) return;
    float imp[NEXP];
    float lb = 0.f, isum = 0.f;
    for (int e = 0; e < NEXP; ++e) {
        imp[e] = aux_f[e];
        isum += imp[e];
        lb += (float)aux_i[e] * imp[e];
    }
    lb *= (float)NEXP / ((float)N_TOK * (float)N_TOK);
    float zl = aux_f[NEXP] / (float)N_TOK;
    float mean = isum / (float)NEXP;
    float var = 0.f;
    for (int e = 0; e < NEXP; ++e) { float d = imp[e] - mean; var += d * d; }
    var /= (float)(NEXP - 1);
    out_tail[0] = lb;
    out_tail[1] = zl;
    out_tail[2] = var;
    for (int e = 0; e < NEXP; ++e) out_tail[3 + e] = (float)aux_i[e];

    int off = 0;
    for (int e = 0; e < NEXP; ++e) {
        offsets[e] = off;
        off += ((aux_i[NEXP + e] + 255) >> 8) << 8;   // 256-aligned expert ranges
    }
    offsets[NEXP] = off;
    int ntile = off >> 8;
    for (int tt = 0; tt < MAXTILE; ++tt) {
        int e = -1;
        if (tt < ntile) {
            for (int j = 0; j < NEXP; ++j)
                if (tt * 256 >= offsets[j] && tt * 256 < offsets[j + 1]) e = j;
        }
        tile_e[tt] = e;
    }
    for (int e = 0; e < NEXP; ++e) cursor[e] = 0;
}

// ---------------- fill: compact (token,k) pairs into per-expert slot ranges ----------------
__global__ void fill_kernel(const int* __restrict__ tok_e, const float* __restrict__ tok_w,
                            const int* __restrict__ offsets, int* __restrict__ cursor,
                            int* __restrict__ slot_token, float* __restrict__ slot_wt)
{
    int t = blockIdx.x * 256 + threadIdx.x;
    if (t >= N_TOK) return;
    for (int k = 0; k < 2; ++k) {
        int e = tok_e[t * 2 + k];
        int pos = atomicAdd(&cursor[e], 1);
        int slot = offsets[e] + pos;
        slot_token[slot] = t;
        slot_wt[slot] = tok_w[t * 2 + k];
    }
}

// ---------------- weight pre-conversion ----------------
// wup[e][h][d] = bf16(wsu[d][h] + wru[e][d][h]); wsu tile read ONCE, e-loop inside.
__global__ __launch_bounds__(256) void convert_up(const float* __restrict__ wsu,
                                                  const float* __restrict__ wru,
                                                  ushort* __restrict__ wup)
{
    int h0 = blockIdx.x * 64, d0 = blockIdx.y * 64;
    __shared__ float tS[64][65];   // wsu[d][h]
    __shared__ float tR[64][65];   // wru[e][d][h]
    int c = threadIdx.x & 63, r4 = threadIdx.x >> 6;
#pragma unroll
    for (int it = 0; it < 16; ++it) {
        int r = it * 4 + r4;
        tS[r][c] = wsu[((size_t)(d0 + r)) * HDIM + h0 + c];
    }
    int c4 = threadIdx.x & 15, rr = threadIdx.x >> 4;
    for (int e = 0; e < NEXP; ++e) {
        __syncthreads();
#pragma unroll
        for (int it = 0; it < 16; ++it) {
            int r = it * 4 + r4;
            tR[r][c] = wru[(size_t)e * DIMD * HDIM + ((size_t)(d0 + r)) * HDIM + h0 + c];
        }
        __syncthreads();
#pragma unroll
        for (int it = 0; it < 4; ++it) {
            int hr = it * 16 + rr;
            ushort4 o;
            o.x = f2bf(tS[c4 * 4 + 0][hr] + tR[c4 * 4 + 0][hr]);
            o.y = f2bf(tS[c4 * 4 + 1][hr] + tR[c4 * 4 + 1][hr]);
            o.z = f2bf(tS[c4 * 4 + 2][hr] + tR[c4 * 4 + 2][hr]);
            o.w = f2bf(tS[c4 * 4 + 3][hr] + tR[c4 * 4 + 3][hr]);
            *(ushort4*)(wup + ((size_t)e * HDIM + h0 + hr) * DIMD + d0 + c4 * 4) = o;
        }
    }
}

// wdn[e][d][h] = bf16(wsd[d][h] + wrd[e][d][h])   (no transpose needed)
__global__ void convert_dn(const float* __restrict__ wsd, const float* __restrict__ wrd,
                           ushort* __restrict__ wdn)
{
    size_t i = ((size_t)blockIdx.x * 256 + threadIdx.x) * 4;
    float4 a = *(const float4*)(wrd + i);
    float4 b = *(const float4*)(wsd + (i & (size_t)0x3FFFFF)); // i mod 2^22 (D*H)
    ushort4 o;
    o.x = f2bf(a.x + b.x); o.y = f2bf(a.y + b.y);
    o.z = f2bf(a.z + b.z); o.w = f2bf(a.w + b.w);
    *(ushort4*)(wdn + i) = o;
}

// ---------------- up GEMM: h = relu(x @ Wup_e)^2, 256x128 tile, BK=64 ----------------
// LDS rows stride 64 ushorts; XOR swizzle folded into DMA source part: slot s of
// row r holds global 16B-part s^(r&7) -> conflict-free ds_read_b128 fragments.
__global__ __launch_bounds__(256, 2) void up_gemm(
    const ushort* __restrict__ xbf, const ushort* __restrict__ wup,
    const int* __restrict__ slot_token, const int* __restrict__ tile_e,
    ushort* __restrict__ hbf)
{
    int bt = blockIdx.y;
    int e = tile_e[bt];
    if (e < 0) return;
    int h0 = blockIdx.x * 128;
    __shared__ ushort As[256 * 64];   // 32 KB
    __shared__ ushort Bs[128 * 64];   // 16 KB
    int t = threadIdx.x, wave = t >> 6, lane = t & 63;
    int s8 = lane & 7, r8 = lane >> 3;
    int p = s8 ^ r8;
    const ushort* wb = wup + ((size_t)e * HDIM + h0) * DIMD;
    const ushort* aptr[8];
    const ushort* bptr[4];
#pragma unroll
    for (int c = 0; c < 8; ++c) {
        int row = wave * 64 + c * 8 + r8;
        int tok = slot_token[bt * 256 + row];
        if (tok < 0) tok = 0;          // padding rows: garbage ok, discarded downstream
        aptr[c] = xbf + (size_t)tok * DIMD + p * 8;
    }
#pragma unroll
    for (int c = 0; c < 4; ++c) {
        int row = wave * 32 + c * 8 + r8;
        bptr[c] = wb + (size_t)row * DIMD + p * 8;
    }
    ushort* lA = As + wave * 64 * 64;
    ushort* lB = Bs + wave * 32 * 64;
    int wm = wave * 64;
    int l15 = lane & 15, q = lane >> 4, r7 = l15 & 7;
    f32x4 acc[4][8] = {};
    for (int k0 = 0; k0 < DIMD; k0 += 64) {
        __syncthreads();
#pragma unroll
        for (int c = 0; c < 8; ++c) async_copy16(aptr[c] + k0, lA + c * 512);
#pragma unroll
        for (int c = 0; c < 4; ++c) async_copy16(bptr[c] + k0, lB + c * 512);
        __syncthreads();
#pragma unroll
        for (int kk = 0; kk < 64; kk += 32) {
            int pr = (kk >> 3) + q;
            int so = ((pr ^ r7) << 3);
            bf16x8 a[4], b[8];
#pragma unroll
            for (int i = 0; i < 4; ++i) a[i] = *(const bf16x8*)(As + (wm + i * 16 + l15) * 64 + so);
#pragma unroll
            for (int j = 0; j < 8; ++j) b[j] = *(const bf16x8*)(Bs + (j * 16 + l15) * 64 + so);
#pragma unroll
            for (int i = 0; i < 4; ++i)
#pragma unroll
                for (int j = 0; j < 8; ++j)
                    acc[i][j] = __builtin_amdgcn_mfma_f32_16x16x32_bf16(a[i], b[j], acc[i][j], 0, 0, 0);
        }
    }
    size_t rowbase = (size_t)bt * 256;
#pragma unroll
    for (int i = 0; i < 4; ++i) {
#pragma unroll
        for (int r = 0; r < 4; ++r) {
            size_t rb = (rowbase + wm + i * 16 + q * 4 + r) * HDIM + h0;
#pragma unroll
            for (int j = 0; j < 8; ++j) {
                float v = acc[i][j][r];
                v = fmaxf(v, 0.f); v = v * v;
                hbf[rb + j * 16 + l15] = f2bf(v);
            }
        }
    }
}

// ---------------- down GEMM: out[token] += wt * (h @ Wdn_e^T), 256x128 tile, K-split x2 ------
__global__ __launch_bounds__(256, 2) void down_gemm(
    const ushort* __restrict__ hbf, const ushort* __restrict__ wdn,
    const int* __restrict__ slot_token, const float* __restrict__ slot_wt,
    const int* __restrict__ tile_e, float* __restrict__ out)
{
    int bt = blockIdx.y;
    int e = tile_e[bt];
    if (e < 0) return;
    int d0 = blockIdx.x * 128;
    int kbase = blockIdx.z * (HDIM / 2);
    __shared__ ushort As[256 * 64];
    __shared__ ushort Bs[128 * 64];
    __shared__ int stok[256];
    __shared__ float swt[256];
    int t = threadIdx.x, wave = t >> 6, lane = t & 63;
    stok[t] = slot_token[bt * 256 + t];
    swt[t]  = slot_wt[bt * 256 + t];
    int s8 = lane & 7, r8 = lane >> 3;
    int p = s8 ^ r8;
    const ushort* aptr[8];
    const ushort* bptr[4];
#pragma unroll
    for (int c = 0; c < 8; ++c) {
        int row = wave * 64 + c * 8 + r8;
        aptr[c] = hbf + ((size_t)bt * 256 + row) * HDIM + p * 8;
    }
#pragma unroll
    for (int c = 0; c < 4; ++c) {
        int row = wave * 32 + c * 8 + r8;
        bptr[c] = wdn + ((size_t)e * DIMD + d0 + row) * HDIM + p * 8;
    }
    ushort* lA = As + wave * 64 * 64;
    ushort* lB = Bs + wave * 32 * 64;
    int wm = wave * 64;
    int l15 = lane & 15, q = lane >> 4, r7 = l15 & 7;
    f32x4 acc[4][8] = {};
    for (int k0 = kbase; k0 < kbase + HDIM / 2; k0 += 64) {
        __syncthreads();
#pragma unroll
        for (int c = 0; c < 8; ++c) async_copy16(aptr[c] + k0, lA + c * 512);
#pragma unroll
        for (int c = 0; c < 4; ++c) async_copy16(bptr[c] + k0, lB + c * 512);
        __syncthreads();
#pragma unroll
        for (int kk = 0; kk < 64; kk += 32) {
            int pr = (kk >> 3) + q;
            int so = ((pr ^ r7) << 3);
            bf16x8 a[4], b[8];
#pragma unroll
            for (int i = 0; i < 4; ++i) a[i] = *(const bf16x8*)(As + (wm + i * 16 + l15) * 64 + so);
#pragma unroll
            for (int j = 0; j < 8; ++j) b[j] = *(const bf16x8*)(Bs + (j * 16 + l15) * 64 + so);
#pragma unroll
            for (int i = 0; i < 4; ++i)
#pragma unroll
                for (int j = 0; j < 8; ++j)
                    acc[i][j] = __builtin_amdgcn_mfma_f32_16x16x32_bf16(a[i], b[j], acc[i][j], 0, 0, 0);
        }
    }
#pragma unroll
    for (int i = 0; i < 4; ++i) {
#pragma unroll
        for (int r = 0; r < 4; ++r) {
            int row = wm + i * 16 + q * 4 + r;
            int tok = stok[row];
            if (tok < 0) continue;
            float wgt = swt[row];
            float* orow = out + (size_t)tok * DIMD + d0;
#pragma unroll
            for (int j = 0; j < 8; ++j)
                atomicAdd(orow + j * 16 + l15, wgt * acc[i][j][r]);
        }
    }
}

extern "C" void kernel_launch(void* const* d_in, const int* in_sizes, int n_in,
                              void* d_out, int out_size, void* d_ws, size_t ws_size,
                              hipStream_t stream)
{
    const float* x   = (const float*)d_in[0];
    const float* rw  = (const float*)d_in[1];
    const float* wsu = (const float*)d_in[2];
    const float* wsd = (const float*)d_in[3];
    const float* wru = (const float*)d_in[4];
    const float* wrd = (const float*)d_in[5];
    float* out = (float*)d_out;

    char* ws = (char*)d_ws;
    size_t off = 0;
    auto alloc = [&](size_t b) { size_t o = off; off = (off + b + 255) & ~(size_t)255; return o; };
    float* aux_f     = (float*)(ws + alloc(16 * 4));          // imp[8], z
    int*   aux_i     = (int*)(ws + alloc(16 * 4));            // cnt1[8], cnt2[8]
    int*   tok_e     = (int*)(ws + alloc(N_TOK * 2 * 4));
    float* tok_w     = (float*)(ws + alloc(N_TOK * 2 * 4));
    int*   offsets   = (int*)(ws + alloc(16 * 4));
    int*   cursor    = (int*)(ws + alloc(8 * 4));
    int*   tile_e    = (int*)(ws + alloc(128 * 4));
    int*   slot_token= (int*)(ws + alloc(MAXSLOT * 4));
    float* slot_wt   = (float*)(ws + alloc(MAXSLOT * 4));
    ushort* xbf      = (ushort*)(ws + alloc((size_t)N_TOK * DIMD * 2));
    ushort* wup      = (ushort*)(ws + alloc((size_t)NEXP * HDIM * DIMD * 2));
    ushort* wdn      = (ushort*)(ws + alloc((size_t)NEXP * DIMD * HDIM * 2));
    ushort* hbf      = (ushort*)(ws + alloc((size_t)MAXSLOT * HDIM * 2));
    (void)ws_size; (void)in_sizes; (void)n_in;

    hipMemsetAsync(d_out, 0, (size_t)out_size * 4, stream);
    hipMemsetAsync(aux_f, 0, 16 * 4, stream);
    hipMemsetAsync(aux_i, 0, 16 * 4, stream);
    hipMemsetAsync(slot_token, 0xFF, MAXSLOT * 4, stream);

    router_kernel<<<N_TOK / 4, 256, 0, stream>>>(x, rw, xbf, tok_e, tok_w, aux_f, aux_i);
    finalize_kernel<<<1, 64, 0, stream>>>(aux_f, aux_i, out + (size_t)N_TOK * DIMD,
                                          offsets, cursor, tile_e);
    fill_kernel<<<N_TOK / 256, 256, 0, stream>>>(tok_e, tok_w, offsets, cursor, slot_token, slot_wt);
    convert_up<<<dim3(HDIM / 64, DIMD / 64), 256, 0, stream>>>(wsu, wru, wup);
    convert_dn<<<(NEXP * DIMD * HDIM) / (256 * 4), 256, 0, stream>>>(wsd, wrd, wdn);
    up_gemm<<<dim3(HDIM / 128, MAXTILE), 256, 0, stream>>>(xbf, wup, slot_token, tile_e, hbf);
    down_gemm<<<dim3(DIMD / 128, MAXTILE, 2), 256, 0, stream>>>(hbf, wdn, slot_token, slot_wt, tile_e, out);
}